// Round 2
// baseline (518.089 us; speedup 1.0000x reference)
//
#include <hip/hip_runtime.h>

// Tensor-product expansion: out[c,i,j,k,l] = tb[c,0,i]*tb[c,1,j]*tb[c,2,k]*tb[c,3,l]
// where tb = tensor + bias.  C=2048, N=4, L=16.  Output 2048*65536 fp32 = 512 MiB.
// Write-bandwidth bound; fill dispatches prove 6.25 TB/s achievable on this buffer
// => kernel floor ~86 us.  This round: plain cached stores (drop the `nt` policy),
// which is the only structural difference vs the 6.25 TB/s fillBuffer path.

#define NC 2048

typedef float f4 __attribute__((ext_vector_type(4)));

__global__ __launch_bounds__(256) void
tpe_kernel(const float* __restrict__ tensor,
           const float* __restrict__ bias,
           float* __restrict__ out) {
    __shared__ float tb[64];
    const int c = blockIdx.x;
    const int t = threadIdx.x;

    // stage tb[c,:,:] = tensor + bias (64 floats) into LDS
    if (t < 64) {
        tb[t] = tensor[c * 64 + t] + bias[c * 64 + t];
    }
    __syncthreads();

    // Per-thread fixed factors: k = (t>>2)&15, l-quad = t&3
    const int k  = (t >> 2) & 15;
    const int lq = (t & 3) * 4;
    const float ck = tb[32 + k];
    f4 v;
    v.x = ck * tb[48 + lq + 0];
    v.y = ck * tb[48 + lq + 1];
    v.z = ck * tb[48 + lq + 2];
    v.w = ck * tb[48 + lq + 3];

    // j = r*4 + wg for r=0..3 : only 4 distinct j-factors per thread — hoist them.
    const int wg = t >> 6;  // wave id within block (0..3)
    const float bj0 = tb[16 + wg];
    const float bj1 = tb[20 + wg];
    const float bj2 = tb[24 + wg];
    const float bj3 = tb[28 + wg];

    // Per-thread base: lanes store 16B each, contiguous 1 KiB per wave.
    float* op = out + (size_t)c * 65536 + t * 4;

    #pragma unroll
    for (int i = 0; i < 16; ++i) {
        const float ai  = tb[i];           // wave-uniform LDS broadcast
        const float ab0 = ai * bj0;
        const float ab1 = ai * bj1;
        const float ab2 = ai * bj2;
        const float ab3 = ai * bj3;
        float* p = op + i * 4096;          // i advances 16 KiB
        f4 o;
        o.x = ab0 * v.x; o.y = ab0 * v.y; o.z = ab0 * v.z; o.w = ab0 * v.w;
        *(f4*)(p)        = o;              // r=0: +0 KiB
        o.x = ab1 * v.x; o.y = ab1 * v.y; o.z = ab1 * v.z; o.w = ab1 * v.w;
        *(f4*)(p + 1024) = o;              // r=1: +4 KiB
        o.x = ab2 * v.x; o.y = ab2 * v.y; o.z = ab2 * v.z; o.w = ab2 * v.w;
        *(f4*)(p + 2048) = o;              // r=2: +8 KiB
        o.x = ab3 * v.x; o.y = ab3 * v.y; o.z = ab3 * v.z; o.w = ab3 * v.w;
        *(f4*)(p + 3072) = o;              // r=3: +12 KiB
    }
}

extern "C" void kernel_launch(void* const* d_in, const int* in_sizes, int n_in,
                              void* d_out, int out_size, void* d_ws, size_t ws_size,
                              hipStream_t stream) {
    const float* tensor = (const float*)d_in[0];
    const float* bias   = (const float*)d_in[1];
    float* out = (float*)d_out;
    tpe_kernel<<<NC, 256, 0, stream>>>(tensor, bias, out);
}